// Round 9
// baseline (59.425 us; speedup 1.0000x reference)
//
#include <hip/hip_runtime.h>
#include <stdint.h>

// BloomFilterer forward:
//   x = 131071*a + 524287*b + 2147483647*c   (int64)
//   repeat rounds(=10): x = hash(x); result &= bit_array[x mod num_bits]
//   out = (int32) !result
//
// Round 9: R8 + tail batching.
//   Rounds 1-4: serial, per-chain early-exit, wave ballot (94% of traffic,
//   throughput-bound at the ~47.5 G lines/s random-service wall — speculation
//   there is pure loss, measured R3/R4).
//   Rounds 5-10: single speculative batch of 6 probes per surviving chain
//   (6.25% of rows) — collapses ~6 serialized latency windows into 1 for
//   +12.5% line traffic.

#define HASH_C1 2146121005ull
#define HASH_C2 2221713035ull
#define NCHAIN 2

__device__ __forceinline__ long long hash_step(long long x) {
    x = x ^ (x >> 16);
    x = (long long)((unsigned long long)x * HASH_C1);
    x = x ^ (x >> 15);
    x = (long long)((unsigned long long)x * HASH_C2);
    x = x ^ (x >> 16);
    return x;
}

// floored mod d (matches jnp.mod): result in [0,d). Barrett M = floor(2^89/d),
// d in (2^27,2^28); corrections in 32-bit.
__device__ __forceinline__ uint32_t mod_d(long long x, uint32_t d,
                                          unsigned long long M) {
    bool neg = x < 0;
    unsigned long long u = neg ? (0ull - (unsigned long long)x)
                               : (unsigned long long)x;
    unsigned long long q = __umul64hi(u, M) >> 25;
    uint32_t rr = (uint32_t)(u - q * (unsigned long long)d);
    if (rr >= d) rr -= d;
    if (rr >= d) rr -= d;
    return neg ? (rr ? d - rr : 0u) : rr;
}

__device__ __forceinline__ bool probe_dyn(const void* bitsv, int bdt, uint32_t idx)
{
    if (bdt == 0)      return ((const uint8_t*)bitsv)[idx] != 0;
    else if (bdt == 1) return ((const uint32_t*)bitsv)[idx] != 0u;
    else               return ((const unsigned long long*)bitsv)[idx] != 0ull;
}

__global__ __launch_bounds__(256, 8) void bloom_mc(
    const void* __restrict__ nbv,
    const void* __restrict__ bitsv,
    const uint32_t* __restrict__ rounds_p,
    int* __restrict__ out,
    int n_rows,
    uint32_t d,
    unsigned long long M)
{
    __shared__ int s_nb64, s_bdt, s_rounds;

    // ---- per-block dtype detection, wave 0, lane-parallel (measured free) ----
    if (threadIdx.x < 64) {
        int lane = threadIdx.x;
        const uint32_t* bw = (const uint32_t*)bitsv;
        bool anyf = false, alli = true, oddz = true;
        #pragma unroll
        for (int j = 0; j < 8; ++j) {
            int i = lane * 8 + j;
            uint32_t w = bw[i];
            if (w == 0x3F800000u) anyf = true;
            if (w > 1u) alli = false;
            if ((i & 1) && w != 0u) oddz = false;
        }
        unsigned long long m_anyf = __ballot(anyf);
        unsigned long long m_alli = __ballot(alli);
        unsigned long long m_oddz = __ballot(oddz);
        const uint32_t* nw = (const uint32_t*)nbv;
        bool odd_nz = (lane < 16) ? (nw[2 * lane + 1] != 0u) : false;
        unsigned long long m_nb = __ballot(odd_nz);
        if (lane == 0) {
            int bdt;
            if (m_anyf != 0ull)       bdt = 1;                         // float32
            else if (m_alli == ~0ull) bdt = (m_oddz == ~0ull) ? 3 : 1; // int64:int32
            else                      bdt = 0;                         // uint8
            s_bdt    = bdt;
            s_nb64   = (m_nb == 0ull) ? 1 : 0;
            s_rounds = (int)rounds_p[0];
        }
    }
    __syncthreads();

    const int nb64   = s_nb64;
    const int bdt    = s_bdt;
    const int rounds = s_rounds;

    const int base_row = blockIdx.x * (256 * NCHAIN) + threadIdx.x;

    long long x[NCHAIN];
    unsigned alive = 0;

    #pragma unroll
    for (int c = 0; c < NCHAIN; ++c) {
        int row = base_row + c * 256;
        x[c] = 0;
        if (row < n_rows) {
            long long base = (long long)row * 3;
            long long a, b, cc;
            if (nb64) {
                const long long* nb = (const long long*)nbv;
                a = nb[base]; b = nb[base + 1]; cc = nb[base + 2];
            } else {
                const int* nb = (const int*)nbv;
                a = nb[base]; b = nb[base + 1]; cc = nb[base + 2];
            }
            x[c] = 131071LL * a + 524287LL * b + 2147483647LL * cc;
            alive |= 1u << c;
        }
    }

    if (rounds == 10) {
        // ---- phase 1: rounds 0..3, serial early-exit ----
        bool done = false;
        #pragma unroll
        for (int r = 0; r < 4; ++r) {
            if (!done) {
                if (__ballot(alive != 0u) == 0ull) { done = true; }
                else {
                    uint32_t idx[NCHAIN];
                    #pragma unroll
                    for (int c = 0; c < NCHAIN; ++c) {
                        x[c] = hash_step(x[c]);
                        idx[c] = ((alive >> c) & 1u) ? mod_d(x[c], d, M) : 0u;
                    }
                    bool bit[NCHAIN];
                    #pragma unroll
                    for (int c = 0; c < NCHAIN; ++c)
                        bit[c] = probe_dyn(bitsv, bdt, idx[c]);
                    #pragma unroll
                    for (int c = 0; c < NCHAIN; ++c)
                        if (!bit[c]) alive &= ~(1u << c);
                }
            }
        }
        // ---- phase 2: rounds 4..9 as one speculative batch of 6/chain ----
        if (__ballot(alive != 0u) != 0ull) {
            uint32_t idx[NCHAIN][6];
            #pragma unroll
            for (int c = 0; c < NCHAIN; ++c) {
                long long xs = x[c];
                bool al = (alive >> c) & 1u;
                #pragma unroll
                for (int j = 0; j < 6; ++j) {
                    xs = hash_step(xs);
                    idx[c][j] = al ? mod_d(xs, d, M) : 0u;
                }
            }
            bool b[NCHAIN][6];
            #pragma unroll
            for (int c = 0; c < NCHAIN; ++c)
                #pragma unroll
                for (int j = 0; j < 6; ++j)
                    b[c][j] = probe_dyn(bitsv, bdt, idx[c][j]);
            #pragma unroll
            for (int c = 0; c < NCHAIN; ++c) {
                bool ok = b[c][0] & b[c][1] & b[c][2] & b[c][3] & b[c][4] & b[c][5];
                if (!ok) alive &= ~(1u << c);
            }
        }
    } else {
        // generic fallback: fully serial early-exit
        for (int r = 0; r < rounds; ++r) {
            if (__ballot(alive != 0u) == 0ull) break;
            uint32_t idx[NCHAIN];
            #pragma unroll
            for (int c = 0; c < NCHAIN; ++c) {
                x[c] = hash_step(x[c]);
                idx[c] = ((alive >> c) & 1u) ? mod_d(x[c], d, M) : 0u;
            }
            bool bit[NCHAIN];
            #pragma unroll
            for (int c = 0; c < NCHAIN; ++c)
                bit[c] = probe_dyn(bitsv, bdt, idx[c]);
            #pragma unroll
            for (int c = 0; c < NCHAIN; ++c)
                if (!bit[c]) alive &= ~(1u << c);
        }
    }

    #pragma unroll
    for (int c = 0; c < NCHAIN; ++c) {
        int row = base_row + c * 256;
        if (row < n_rows)
            out[row] = ((alive >> c) & 1u) ? 0 : 1;
    }
}

extern "C" void kernel_launch(void* const* d_in, const int* in_sizes, int n_in,
                              void* d_out, int out_size, void* d_ws, size_t ws_size,
                              hipStream_t stream)
{
    const void* nb       = d_in[0];
    const void* bits     = d_in[1];
    // d_in[2] = mersenne (1,3) — constants hardcoded
    const uint32_t* rnds = (const uint32_t*)d_in[3];

    int n_rows  = in_sizes[0] / 3;
    uint32_t d  = (uint32_t)in_sizes[1];    // num_bits = 143,775,876

    unsigned long long M =
        (unsigned long long)(((unsigned __int128)1 << 89) / (unsigned long long)d);

    int rows_per_block = 256 * NCHAIN;
    int blocks = (n_rows + rows_per_block - 1) / rows_per_block;
    bloom_mc<<<blocks, 256, 0, stream>>>(nb, bits, rnds, (int*)d_out,
                                         n_rows, d, M);
}

// Round 10
// 55.324 us; speedup vs baseline: 1.0741x; 1.0741x over previous
//
#include <hip/hip_runtime.h>
#include <stdint.h>

// BloomFilterer forward:
//   x = 131071*a + 524287*b + 2147483647*c   (int64)
//   repeat rounds(=10): x = hash(x); result &= bit_array[x mod num_bits]
//   out = (int32) !result
//
// Round 10: REVERT to R8 — the measured optimum.
// Final model (5 schedules measured): time = lines/57.5G + ~20us.
//   - bit_array is 4-byte bools (R7 marker), 575 MB > 256 MB L3: probes are
//     uniform-random 64B-line traffic; service path saturated whole-kernel.
//   - Minimal traffic = 2.07M lines (E[probes/row]=2.0 at density 0.5) is the
//     algorithmic floor; every speculative line costs full service time
//     (R3 +50% traffic -> +32%; R4 +160% -> +104%; R9 tail +12.5% -> +6.5%).
//   - Latency term (~20us) already minimized at 32 waves/CU (R5: 16 waves/CU
//     costs +6us; tail batching to cut it costs more in traffic than it saves).

#define HASH_C1 2146121005ull
#define HASH_C2 2221713035ull
#define NCHAIN 2

__device__ __forceinline__ long long hash_step(long long x) {
    x = x ^ (x >> 16);
    x = (long long)((unsigned long long)x * HASH_C1);
    x = x ^ (x >> 15);
    x = (long long)((unsigned long long)x * HASH_C2);
    x = x ^ (x >> 16);
    return x;
}

// floored mod d (matches jnp.mod): result in [0,d). Barrett M = floor(2^89/d),
// d in (2^27,2^28) -> q within 2 of truth; corrections done in 32-bit.
__device__ __forceinline__ uint32_t mod_d(long long x, uint32_t d,
                                          unsigned long long M) {
    bool neg = x < 0;
    unsigned long long u = neg ? (0ull - (unsigned long long)x)
                               : (unsigned long long)x;
    unsigned long long q = __umul64hi(u, M) >> 25;
    uint32_t rr = (uint32_t)(u - q * (unsigned long long)d);
    if (rr >= d) rr -= d;
    if (rr >= d) rr -= d;
    return neg ? (rr ? d - rr : 0u) : rr;
}

__device__ __forceinline__ bool probe_dyn(const void* bitsv, int bdt, uint32_t idx)
{
    if (bdt == 0)      return ((const uint8_t*)bitsv)[idx] != 0;
    else if (bdt == 1) return ((const uint32_t*)bitsv)[idx] != 0u;
    else               return ((const unsigned long long*)bitsv)[idx] != 0ull;
}

__global__ __launch_bounds__(256, 8) void bloom_mc(
    const void* __restrict__ nbv,
    const void* __restrict__ bitsv,
    const uint32_t* __restrict__ rounds_p,
    int* __restrict__ out,
    int n_rows,
    uint32_t d,
    unsigned long long M)
{
    __shared__ int s_nb64, s_bdt, s_rounds;

    // ---- per-block dtype detection, wave 0, lane-parallel (measured free) ----
    if (threadIdx.x < 64) {
        int lane = threadIdx.x;
        const uint32_t* bw = (const uint32_t*)bitsv;
        bool anyf = false, alli = true, oddz = true;
        #pragma unroll
        for (int j = 0; j < 8; ++j) {
            int i = lane * 8 + j;
            uint32_t w = bw[i];
            if (w == 0x3F800000u) anyf = true;
            if (w > 1u) alli = false;
            if ((i & 1) && w != 0u) oddz = false;
        }
        unsigned long long m_anyf = __ballot(anyf);
        unsigned long long m_alli = __ballot(alli);
        unsigned long long m_oddz = __ballot(oddz);
        const uint32_t* nw = (const uint32_t*)nbv;
        bool odd_nz = (lane < 16) ? (nw[2 * lane + 1] != 0u) : false;
        unsigned long long m_nb = __ballot(odd_nz);
        if (lane == 0) {
            int bdt;
            if (m_anyf != 0ull)       bdt = 1;                         // float32
            else if (m_alli == ~0ull) bdt = (m_oddz == ~0ull) ? 3 : 1; // int64:int32
            else                      bdt = 0;                         // uint8
            s_bdt    = bdt;
            s_nb64   = (m_nb == 0ull) ? 1 : 0;
            s_rounds = (int)rounds_p[0];
        }
    }
    __syncthreads();

    const int nb64   = s_nb64;
    const int bdt    = s_bdt;
    const int rounds = s_rounds;

    const int base_row = blockIdx.x * (256 * NCHAIN) + threadIdx.x;

    long long x[NCHAIN];
    unsigned alive = 0;

    #pragma unroll
    for (int c = 0; c < NCHAIN; ++c) {
        int row = base_row + c * 256;
        x[c] = 0;
        if (row < n_rows) {
            long long base = (long long)row * 3;
            long long a, b, cc;
            if (nb64) {
                const long long* nb = (const long long*)nbv;
                a = nb[base]; b = nb[base + 1]; cc = nb[base + 2];
            } else {
                const int* nb = (const int*)nbv;
                a = nb[base]; b = nb[base + 1]; cc = nb[base + 2];
            }
            x[c] = 131071LL * a + 524287LL * b + 2147483647LL * cc;
            alive |= 1u << c;
        }
    }

    for (int r = 0; r < rounds; ++r) {
        if (__ballot(alive != 0u) == 0ull) break;

        uint32_t idx[NCHAIN];
        #pragma unroll
        for (int c = 0; c < NCHAIN; ++c) {
            x[c] = hash_step(x[c]);
            idx[c] = ((alive >> c) & 1u) ? mod_d(x[c], d, M) : 0u;
        }
        // independent gathers issued back-to-back (dead chains: line 0, ~free)
        bool bit[NCHAIN];
        #pragma unroll
        for (int c = 0; c < NCHAIN; ++c)
            bit[c] = probe_dyn(bitsv, bdt, idx[c]);
        #pragma unroll
        for (int c = 0; c < NCHAIN; ++c)
            if (!bit[c]) alive &= ~(1u << c);
    }

    #pragma unroll
    for (int c = 0; c < NCHAIN; ++c) {
        int row = base_row + c * 256;
        if (row < n_rows)
            out[row] = ((alive >> c) & 1u) ? 0 : 1;
    }
}

extern "C" void kernel_launch(void* const* d_in, const int* in_sizes, int n_in,
                              void* d_out, int out_size, void* d_ws, size_t ws_size,
                              hipStream_t stream)
{
    const void* nb       = d_in[0];
    const void* bits     = d_in[1];
    // d_in[2] = mersenne (1,3) — constants hardcoded
    const uint32_t* rnds = (const uint32_t*)d_in[3];

    int n_rows  = in_sizes[0] / 3;
    uint32_t d  = (uint32_t)in_sizes[1];    // num_bits = 143,775,876

    unsigned long long M =
        (unsigned long long)(((unsigned __int128)1 << 89) / (unsigned long long)d);

    int rows_per_block = 256 * NCHAIN;
    int blocks = (n_rows + rows_per_block - 1) / rows_per_block;
    bloom_mc<<<blocks, 256, 0, stream>>>(nb, bits, rnds, (int*)d_out,
                                         n_rows, d, M);
}